// Round 11
// baseline (53974.194 us; speedup 1.0000x reference)
//
#include <hip/hip_runtime.h>

#define EPSF 1e-5f

typedef unsigned short u16;
typedef unsigned int u32;

__device__ __forceinline__ u16 f2bf(float f) {
  u32 u = __float_as_uint(f);
  u += 0x7fffu + ((u >> 16) & 1u);   // RNE
  return (u16)(u >> 16);
}
__device__ __forceinline__ u32 packbf(float lo, float hi) {
  return (u32)f2bf(lo) | ((u32)f2bf(hi) << 16);
}

#if __has_builtin(__builtin_amdgcn_fdot2_f32_bf16)
typedef __attribute__((ext_vector_type(2))) __bf16 bf16x2;
__device__ __forceinline__ float dot2bf(u32 w, u32 h, float acc) {
  union { u32 u; bf16x2 v; } a, b; a.u = w; b.u = h;
  return __builtin_amdgcn_fdot2_f32_bf16(a.v, b.v, acc, false);
}
#else
__device__ __forceinline__ float dot2bf(u32 w, u32 h, float acc) {
  float r = fmaf(__uint_as_float(w << 16), __uint_as_float(h << 16), acc);
  return fmaf(__uint_as_float(w & 0xffff0000u), __uint_as_float(h & 0xffff0000u), r);
}
#endif

// W1p: u16 idx (kk*1024 + j)*8 + r = bf16(W1[j][kk*8+r]), kk 0..63 (lane-coalesced 16B)
// W2p: u16 idx (kk*512  + n)*8 + r = bf16(W2[n][kk*8+r]), kk 0..63
__global__ void prep_weights(const float* __restrict__ W1, const float* __restrict__ W2,
                             u16* __restrict__ W1p, u16* __restrict__ W2p) {
  int i = blockIdx.x * blockDim.x + threadIdx.x;
  if (i < 1024 * 64) {
    int j = i >> 6, kk = i & 63;
    const float* src = W1 + (size_t)j * 512 + kk * 8;
    u16* dst = W1p + ((size_t)(kk * 1024 + j)) * 8;
    #pragma unroll
    for (int r = 0; r < 8; ++r) dst[r] = f2bf(src[r]);
  }
  if (i < 512 * 64) {
    int n = i >> 6, kk = i & 63;
    const float* src = W2 + (size_t)n * 512 + kk * 8;
    u16* dst = W2p + ((size_t)(kk * 512 + n)) * 8;
    #pragma unroll
    for (int r = 0; r < 8; ++r) dst[r] = f2bf(src[r]);
  }
}

// 64 blocks (one per batch row) x 512 threads (8 waves), 128-VGPR cap.
// Thread tid owns mm1 outputs j=tid and j=tid+512, and mm2 output n=tid.
// Depth-2 ping-pong with 2-chunk groups: buffers Aa/Ab/Ba/Bb = 32 VGPRs (live ~92 < 128).
__global__ __launch_bounds__(512, 1)
void rnn_kernel(const float* __restrict__ xs, const float* __restrict__ h0,
                const float* __restrict__ gamma, const float* __restrict__ beta,
                const u16* __restrict__ W1p,
                const float* __restrict__ lnh_w, const float* __restrict__ lnh_b,
                const u16* __restrict__ W2p,
                const float* __restrict__ lnx_w, const float* __restrict__ lnx_b,
                float* __restrict__ out) {
  const int r = blockIdx.x;
  const int tid = threadIdx.x;
  const int w = tid >> 6, lane = tid & 63;
  const int N = 512;

  __shared__ u32 hb2[256];
  __shared__ u32 xb2[256];
  __shared__ float red_s[8], red_q[8];
  __shared__ __align__(16) float out_t[32][512];   // 64 KB

  const float w1w_i = lnh_w[tid],       w1b_i = lnh_b[tid];
  const float w1w_g = lnh_w[512 + tid], w1b_g = lnh_b[512 + tid];
  const float g0 = gamma[0 * N + tid], g1 = gamma[1 * N + tid], g2 = gamma[2 * N + tid];
  const float b0 = beta[0 * N + tid],  b1 = beta[1 * N + tid],  b2 = beta[2 * N + tid];
  const float w2w = lnx_w[tid], w2b = lnx_b[tid];

  float h_v = h0[(size_t)r * N + tid];
  {
    float hnb = __shfl_down(h_v, 1);
    if (!(tid & 1)) hb2[tid >> 1] = packbf(h_v, hnb);
  }
  const float* xs_b = xs + (size_t)r * 3 * N * 1024;
  const uint4* wpa = ((const uint4*)W1p) + tid;          // elem kk at [kk*1024]
  const uint4* wpb = ((const uint4*)W1p) + tid + 512;
  const uint4* wp2 = ((const uint4*)W2p) + tid;          // elem kk at [kk*512]
  __syncthreads();

// 2-chunk groups, depth-2 ping-pong (buffers of 2 uint4 per stream)
#define M1L(DA, DB, g)                                         \
  _Pragma("unroll") for (int u = 0; u < 2; ++u) {              \
    DA[u] = wpa[((g) * 2 + u) * 1024];                         \
    DB[u] = wpb[((g) * 2 + u) * 1024];                         \
  }
#define M1C(SA, SB, g)                                         \
  _Pragma("unroll") for (int u = 0; u < 2; ++u) {              \
    uint4 h4 = hp4[(g) * 2 + u];                               \
    i0 = dot2bf(SA[u].x, h4.x, i0); i1 = dot2bf(SA[u].y, h4.y, i1); \
    i2 = dot2bf(SA[u].z, h4.z, i2); i3 = dot2bf(SA[u].w, h4.w, i3); \
    e0 = dot2bf(SB[u].x, h4.x, e0); e1 = dot2bf(SB[u].y, h4.y, e1); \
    e2 = dot2bf(SB[u].z, h4.z, e2); e3 = dot2bf(SB[u].w, h4.w, e3); \
  }
#define M2L(D, g)                                              \
  _Pragma("unroll") for (int u = 0; u < 2; ++u) {              \
    D[u] = wp2[((g) * 2 + u) * 512];                           \
  }
#define M2C(S, g)                                              \
  _Pragma("unroll") for (int u = 0; u < 2; ++u) {              \
    uint4 x4 = xp4[(g) * 2 + u];                               \
    c0 = dot2bf(S[u].x, x4.x, c0); c1r = dot2bf(S[u].y, x4.y, c1r); \
    c2 = dot2bf(S[u].z, x4.z, c2); c3 = dot2bf(S[u].w, x4.w, c3); \
  }

  for (int t0 = 0; t0 < 1024; t0 += 4) {
    float4 xr0 = *(const float4*)(xs_b + (size_t)(0 * N + tid) * 1024 + t0);
    float4 xr1 = *(const float4*)(xs_b + (size_t)(1 * N + tid) * 1024 + t0);
    float4 xr2 = *(const float4*)(xs_b + (size_t)(2 * N + tid) * 1024 + t0);
    #pragma unroll
    for (int q = 0; q < 4; ++q) {
      const int t = t0 + q;
      const int tt = t & 31;

      // ---- in_layer (regs) ----
      float il;
      {
        float s0 = 1.f / (1.f + __expf(-(g0 * h_v + b0)));
        float s1 = 1.f / (1.f + __expf(-(g1 * h_v + b1)));
        float s2 = 1.f / (1.f + __expf(-(g2 * h_v + b2)));
        float x0 = (q == 0) ? xr0.x : (q == 1) ? xr0.y : (q == 2) ? xr0.z : xr0.w;
        float x1 = (q == 0) ? xr1.x : (q == 1) ? xr1.y : (q == 2) ? xr1.z : xr1.w;
        float x2 = (q == 0) ? xr2.x : (q == 1) ? xr2.y : (q == 2) ? xr2.z : xr2.w;
        il = fmaxf(s0 * x0 + s1 * x1 + s2 * x2, 0.f);
      }

      // ---- mm1: two j-streams, 32 groups, depth-2 ping-pong ----
      float acc_i, acc_g;
      {
        const uint4* hp4 = (const uint4*)hb2;     // wave-uniform broadcast
        uint4 Aa[2], Ab[2], Ba[2], Bb[2];
        float i0 = 0, i1 = 0, i2 = 0, i3 = 0;
        float e0 = 0, e1 = 0, e2 = 0, e3 = 0;
        M1L(Aa, Ab, 0);
        #pragma unroll
        for (int g = 0; g < 15; ++g) {
          M1L(Ba, Bb, 2 * g + 1); M1C(Aa, Ab, 2 * g);
          M1L(Aa, Ab, 2 * g + 2); M1C(Ba, Bb, 2 * g + 1);
        }
        M1L(Ba, Bb, 31); M1C(Aa, Ab, 30);
        M1C(Ba, Bb, 31);
        acc_i = (i0 + i1) + (i2 + i3);
        acc_g = (e0 + e1) + (e2 + e3);
      }

      // ---- LN1 stats over 1024 (both halves per thread) ----
      {
        float s = acc_i + acc_g, qq = acc_i * acc_i + acc_g * acc_g;
        #pragma unroll
        for (int off = 32; off > 0; off >>= 1) {
          s += __shfl_down(s, off); qq += __shfl_down(qq, off);
        }
        if (lane == 0) { red_s[w] = s; red_q[w] = qq; }
      }
      __syncthreads();                                   // B1
      float mu1, rinv1;
      {
        float s = red_s[tid & 7], qq = red_q[tid & 7];
        #pragma unroll
        for (int off = 4; off > 0; off >>= 1) {
          s += __shfl_xor(s, off); qq += __shfl_xor(qq, off);
        }
        mu1 = s * (1.f / 1024.f);
        rinv1 = rsqrtf(qq * (1.f / 1024.f) - mu1 * mu1 + EPSF);
      }

      // ---- LN1 apply ----
      float x_v = fmaxf(il + (acc_i - mu1) * rinv1 * w1w_i + w1b_i, 0.f);
      float hg_n = (acc_g - mu1) * rinv1 * w1w_g + w1b_g;
      {
        float xnb = __shfl_down(x_v, 1);
        if (!(tid & 1)) xb2[tid >> 1] = packbf(x_v, xnb);
      }
      __syncthreads();                                   // B2

      // ---- mm2: one n-stream, 32 groups, depth-2 ping-pong ----
      float accf;
      {
        const uint4* xp4 = (const uint4*)xb2;
        uint4 A2[2], B2[2];
        float c0 = 0, c1r = 0, c2 = 0, c3 = 0;
        M2L(A2, 0);
        #pragma unroll
        for (int g = 0; g < 15; ++g) {
          M2L(B2, 2 * g + 1); M2C(A2, 2 * g);
          M2L(A2, 2 * g + 2); M2C(B2, 2 * g + 1);
        }
        M2L(B2, 31); M2C(A2, 30);
        M2C(B2, 31);
        accf = (c0 + c1r) + (c2 + c3);
      }

      // ---- LN2 stats over 512 ----
      {
        float s = accf, qq = accf * accf;
        #pragma unroll
        for (int off = 32; off > 0; off >>= 1) {
          s += __shfl_down(s, off); qq += __shfl_down(qq, off);
        }
        if (lane == 0) { red_s[w] = s; red_q[w] = qq; }
      }
      __syncthreads();                                   // B3
      {
        float s = red_s[tid & 7], qq = red_q[tid & 7];
        #pragma unroll
        for (int off = 4; off > 0; off >>= 1) {
          s += __shfl_xor(s, off); qq += __shfl_xor(qq, off);
        }
        float mu2 = s * (1.f / 512.f);
        float rinv2 = rsqrtf(qq * (1.f / 512.f) - mu2 * mu2 + EPSF);

        // ---- gate + state update ----
        float y = (accf - mu2) * rinv2 * w2w + w2b;
        float gg = 1.f / (1.f + __expf(-(y + hg_n)));
        float hn = h_v + gg * (x_v - h_v);
        out_t[tt][tid] = hn;
        h_v = hn;
        float hnb = __shfl_down(hn, 1);
        if (!(tid & 1)) hb2[tid >> 1] = packbf(hn, hnb);
      }
      __syncthreads();                                   // B4

      // ---- flush every 32 steps: thread tid owns row n=tid ----
      if (tt == 31) {
        float* op = out + ((size_t)r * N + tid) * 1024 + (t - 31);
        #pragma unroll
        for (int i = 0; i < 8; ++i) {
          float4 v;
          v.x = out_t[i * 4 + 0][tid];
          v.y = out_t[i * 4 + 1][tid];
          v.z = out_t[i * 4 + 2][tid];
          v.w = out_t[i * 4 + 3][tid];
          *(float4*)(op + i * 4) = v;
        }
      }
    }
  }
}

extern "C" void kernel_launch(void* const* d_in, const int* in_sizes, int n_in,
                              void* d_out, int out_size, void* d_ws, size_t ws_size,
                              hipStream_t stream) {
  const float* xs    = (const float*)d_in[0];
  const float* h0    = (const float*)d_in[1];
  const float* gamma = (const float*)d_in[2];
  const float* beta  = (const float*)d_in[3];
  const float* W1    = (const float*)d_in[4];
  const float* lnh_w = (const float*)d_in[5];
  const float* lnh_b = (const float*)d_in[6];
  const float* W2    = (const float*)d_in[7];
  const float* lnx_w = (const float*)d_in[8];
  const float* lnx_b = (const float*)d_in[9];
  float* out = (float*)d_out;

  u16* W1p = (u16*)d_ws;                    // 1 MB
  u16* W2p = W1p + (size_t)1024 * 512;      // 0.5 MB

  prep_weights<<<(65536 + 255) / 256, 256, 0, stream>>>(W1, W2, W1p, W2p);
  rnn_kernel<<<64, 512, 0, stream>>>(xs, h0, gamma, beta, W1p,
                                     lnh_w, lnh_b, W2p, lnx_w, lnx_b, out);
}